// Round 1
// baseline (453.257 us; speedup 1.0000x reference)
//
#include <hip/hip_runtime.h>

#define S_LEN 512
#define H_DIM 128
#define C_DIM 10

typedef __attribute__((ext_vector_type(8))) short short8;
typedef __attribute__((ext_vector_type(4))) float f32x4;

__device__ __forceinline__ unsigned short f2bf(float f) {
    union { float f; unsigned u; } v; v.f = f;
    return (unsigned short)((v.u + 0x7FFFu + ((v.u >> 16) & 1u)) >> 16);
}

__device__ __forceinline__ float fast_sigmoid(float x) {
    float e = __builtin_amdgcn_exp2f(-1.4426950408889634f * x);
    return __builtin_amdgcn_rcpf(1.0f + e);
}
__device__ __forceinline__ float fast_tanh(float x) {
    float e = __builtin_amdgcn_exp2f(2.8853900817779268f * x);  // e^{2x}
    return 1.0f - 2.0f * __builtin_amdgcn_rcpf(e + 1.0f);
}

// 64 blocks x 512 threads (8 waves). Block owns 16 batch rows for all 512
// steps. Wave w owns gate-columns j in [16w,16w+16) of ALL FOUR gates
// (N-tiles {w, w+8, w+16, w+24} of the concatenated [16,512] gate matrix),
// so the c/h update is fully in-register. Wh lives in registers as MFMA
// B-fragments (bf16) for the whole kernel. Only h goes through LDS
// (double-buffered bf16, XOR-swizzled 16B chunks for conflict-free
// ds_read_b128 A-fragment loads).
__global__ __launch_bounds__(512, 2) void lstm_fused(
    const float* __restrict__ x,
    const float* __restrict__ Wgx, const float* __restrict__ Wgh,
    const float* __restrict__ Wix, const float* __restrict__ Wih,
    const float* __restrict__ Wfx, const float* __restrict__ Wfh,
    const float* __restrict__ Wox, const float* __restrict__ Woh,
    const float* __restrict__ Wph,
    const float* __restrict__ bg, const float* __restrict__ bi,
    const float* __restrict__ bff, const float* __restrict__ bo,
    const float* __restrict__ bp,
    float* __restrict__ out)
{
    __shared__ float xT[S_LEN][16];              // 32 KB, x tile transposed
    __shared__ unsigned short hb[2][16 * H_DIM]; // 2 x 4 KB bf16 h (swizzled)
    __shared__ float hfin[16][132];              // final h fp32 (padded)

    const int tid  = threadIdx.x;
    const int lane = tid & 63;
    const int w    = tid >> 6;        // wave 0..7
    const int b0   = blockIdx.x * 16; // batch row base

    // ---- stage x tile transposed: xT[t][row] ----
    {
        const int r  = tid >> 5;          // 0..15
        const int t0 = (tid & 31) * 16;   // 0..496
        const float* xp = x + (b0 + r) * S_LEN + t0;
        #pragma unroll
        for (int i2 = 0; i2 < 16; ++i2) xT[t0 + i2][r] = xp[i2];
    }
    // zero h buffer 0 (h0 = 0)
    for (int i2 = tid; i2 < 16 * H_DIM; i2 += 512) hb[0][i2] = 0;

    const int jl = lane & 15;   // col within 16-wide tile
    const int kg = lane >> 4;   // 0..3 (k-group / row-group)
    const int j  = w * 16 + jl; // h-column 0..127 owned by this lane

    // ---- Wh into registers as B-fragments: B[k][n=j], bf16 ----
    // B-frag lane l, elem e:  k = 32*kk + 8*(l>>4) + e, n = l&15 (col j)
    const float* WhA[4] = { Wgh, Wih, Wfh, Woh };
    short8 bfrag[4][4];
    #pragma unroll
    for (int g = 0; g < 4; ++g) {
        #pragma unroll
        for (int kk = 0; kk < 4; ++kk) {
            const float* src = WhA[g] + (kk * 32 + kg * 8) * H_DIM + j;
            short8 v;
            #pragma unroll
            for (int e = 0; e < 8; ++e) v[e] = (short)f2bf(src[e * H_DIM]);
            bfrag[g][kk] = v;
        }
    }
    const float wxv[4] = { Wgx[j], Wix[j], Wfx[j], Wox[j] };
    const float bv[4]  = { bg[j],  bi[j],  bff[j], bo[j]  };

    // A-frag read offsets (elements): A[m = lane&15][k = 8*kg + 32*kk]
    // 16B chunk index = k/8 = kg + 4*kk, swizzled by XOR with (row&7)
    int aoff[4];
    #pragma unroll
    for (int kk = 0; kk < 4; ++kk) {
        const int chunk = kg + 4 * kk;
        aoff[kk] = (lane & 15) * H_DIM + ((chunk ^ (lane & 7)) << 3);
    }
    // h write offsets: row = 4*kg + r, col = j (same swizzle)
    int woff[4];
    #pragma unroll
    for (int r = 0; r < 4; ++r) {
        const int row = 4 * kg + r;
        woff[r] = row * H_DIM + (((j >> 3) ^ (row & 7)) << 3) + (j & 7);
    }

    float cst[4]   = { 0.f, 0.f, 0.f, 0.f };  // cell state (rows 4*kg+r, col j)
    float hlast[4] = { 0.f, 0.f, 0.f, 0.f };

    __syncthreads();

    int buf = 0;
    for (int t = 0; t < S_LEN; ++t) {
        // A-fragments (shared h) from LDS
        short8 afr[4];
        #pragma unroll
        for (int kk = 0; kk < 4; ++kk)
            afr[kk] = *(const short8*)&hb[buf][aoff[kk]];

        f32x4 acc[4] = {};  // one 16x16 tile per gate
        #pragma unroll
        for (int kk = 0; kk < 4; ++kk) {
            #pragma unroll
            for (int g = 0; g < 4; ++g)
                acc[g] = __builtin_amdgcn_mfma_f32_16x16x32_bf16(
                             afr[kk], bfrag[g][kk], acc[g], 0, 0, 0);
        }

        // x[row][t] for rows 4*kg..4*kg+3 (broadcast read)
        const f32x4 xv = *(const f32x4*)&xT[t][kg * 4];

        // activations + state update, all in-register
        #pragma unroll
        for (int r = 0; r < 4; ++r) {
            const float pg = acc[0][r] + xv[r] * wxv[0] + bv[0];
            const float pi = acc[1][r] + xv[r] * wxv[1] + bv[1];
            const float pf = acc[2][r] + xv[r] * wxv[2] + bv[2];
            const float po = acc[3][r] + xv[r] * wxv[3] + bv[3];
            const float tg = fast_tanh(pg);
            const float si = fast_sigmoid(pi);
            const float sf = fast_sigmoid(pf);
            const float so = fast_sigmoid(po);
            const float cn = tg * si + cst[r] * sf;
            cst[r] = cn;
            const float hn = fast_tanh(cn) * so;
            hlast[r] = hn;
            hb[buf ^ 1][woff[r]] = f2bf(hn);
        }
        __syncthreads();
        buf ^= 1;
    }

    // ---- epilogue: logits = h_last @ W_ph + b_p (fp32 h) ----
    #pragma unroll
    for (int r = 0; r < 4; ++r) hfin[4 * kg + r][j] = hlast[r];
    __syncthreads();

    if (tid < 160) {
        const int b = tid / 10, cc = tid % 10;
        float s = bp[cc];
        #pragma unroll 4
        for (int k = 0; k < H_DIM; ++k) s += hfin[b][k] * Wph[k * C_DIM + cc];
        out[(b0 + b) * C_DIM + cc] = s;
    }
}

extern "C" void kernel_launch(void* const* d_in, const int* in_sizes, int n_in,
                              void* d_out, int out_size, void* d_ws, size_t ws_size,
                              hipStream_t stream) {
    const float* x   = (const float*)d_in[0];
    const float* Wgx = (const float*)d_in[1];
    const float* Wgh = (const float*)d_in[2];
    const float* Wix = (const float*)d_in[3];
    const float* Wih = (const float*)d_in[4];
    const float* Wfx = (const float*)d_in[5];
    const float* Wfh = (const float*)d_in[6];
    const float* Wox = (const float*)d_in[7];
    const float* Woh = (const float*)d_in[8];
    const float* Wph = (const float*)d_in[9];
    const float* bg  = (const float*)d_in[10];
    const float* bi  = (const float*)d_in[11];
    const float* bf  = (const float*)d_in[12];
    const float* bo  = (const float*)d_in[13];
    const float* bp  = (const float*)d_in[14];
    float* out = (float*)d_out;

    lstm_fused<<<dim3(64), dim3(512), 0, stream>>>(
        x, Wgx, Wgh, Wix, Wih, Wfx, Wfh, Wox, Woh, Wph,
        bg, bi, bf, bo, bp, out);
}

// Round 2
// 218.032 us; speedup vs baseline: 2.0789x; 2.0789x over previous
//
#include <hip/hip_runtime.h>

#define S_LEN 512
#define H_DIM 128
#define C_DIM 10

typedef __attribute__((ext_vector_type(8))) short short8;
typedef __attribute__((ext_vector_type(4))) float f32x4;

__device__ __forceinline__ unsigned short f2bf(float f) {
    union { float f; unsigned u; } v; v.f = f;
    return (unsigned short)((v.u + 0x7FFFu + ((v.u >> 16) & 1u)) >> 16);
}

__device__ __forceinline__ float fast_sigmoid(float x) {
    float e = __builtin_amdgcn_exp2f(-1.4426950408889634f * x);
    return __builtin_amdgcn_rcpf(1.0f + e);
}
__device__ __forceinline__ float fast_tanh(float x) {
    float e = __builtin_amdgcn_exp2f(2.8853900817779268f * x);  // e^{2x}
    return 1.0f - 2.0f * __builtin_amdgcn_rcpf(e + 1.0f);
}

// 256 blocks x 512 threads (8 waves). Block owns 4 batch rows for all 512
// steps (256/256 CUs active). Batch row b sits at MFMA M-row 4b, so for
// every lane (kg = lane>>4, jl = lane&15) acc[g][0] is the valid gate value
// (batch kg, column w*16+jl) -> all 64 lanes do exactly one activation.
// M-rows not divisible by 4 are permanently zero: only lanes with
// (lane&3)==0 re-read A-fragments each step (16 lanes x 16B per read).
// Wh stays in registers as bf16 B-fragments for the whole kernel; h goes
// through a compact double-buffered LDS tile hb[4][136] (row pad = 16B ->
// conflict-free 16-lane ds_read_b128).
__global__ __launch_bounds__(512, 2) void lstm_fused(
    const float* __restrict__ x,
    const float* __restrict__ Wgx, const float* __restrict__ Wgh,
    const float* __restrict__ Wix, const float* __restrict__ Wih,
    const float* __restrict__ Wfx, const float* __restrict__ Wfh,
    const float* __restrict__ Wox, const float* __restrict__ Woh,
    const float* __restrict__ Wph,
    const float* __restrict__ bg, const float* __restrict__ bi,
    const float* __restrict__ bff, const float* __restrict__ bo,
    const float* __restrict__ bp,
    float* __restrict__ out)
{
    __shared__ float xT[S_LEN][5];                                  // pad-5: conflict-free
    __shared__ __attribute__((aligned(16))) unsigned short hb[2][4][136]; // bf16 h, row pad 16B
    __shared__ float hfin[4][H_DIM];

    const int tid  = threadIdx.x;
    const int lane = tid & 63;
    const int w    = tid >> 6;        // wave 0..7
    const int b0   = blockIdx.x * 4;  // batch row base

    // ---- stage x transposed: xT[t][r] = x[b0+r][t] (coalesced reads) ----
    {
        const float* xp = x + b0 * S_LEN + tid;
        #pragma unroll
        for (int r = 0; r < 4; ++r) xT[tid][r] = xp[r * S_LEN];
    }
    // zero h buffer 0
    {
        unsigned short* hz = &hb[0][0][0];
        for (int i2 = tid; i2 < 4 * 136; i2 += 512) hz[i2] = 0;
    }

    const int jl = lane & 15;   // col within 16-wide tile
    const int kg = lane >> 4;   // 0..3
    const int j  = w * 16 + jl; // h-column 0..127 owned by this lane

    // ---- Wh into registers as B-fragments: B[k][n=j], bf16 ----
    // B-frag lane l elem e: k = 32*kk + 8*(l>>4) + e, n = l&15
    const float* WhA[4] = { Wgh, Wih, Wfh, Woh };
    short8 bfrag[4][4];
    #pragma unroll
    for (int g = 0; g < 4; ++g) {
        #pragma unroll
        for (int kk = 0; kk < 4; ++kk) {
            const float* src = WhA[g] + (kk * 32 + kg * 8) * H_DIM + j;
            short8 v;
            #pragma unroll
            for (int e = 0; e < 8; ++e) v[e] = (short)f2bf(src[e * H_DIM]);
            bfrag[g][kk] = v;
        }
    }
    const float wxv[4] = { Wgx[j], Wix[j], Wfx[j], Wox[j] };
    const float bv[4]  = { bg[j],  bi[j],  bff[j], bo[j]  };

    // A-frag source: active lanes (lane&3)==0 read batch row (lane&15)>>2
    // at k-chunk = 32*kk + 8*(lane>>4). Byte offset inside one hb buffer:
    const bool aActive = (lane & 3) == 0;
    const int  abase   = ((lane & 15) >> 2) * 272 + (lane >> 4) * 16; // +kk*64

    float cst  = 0.f;   // cell state for (batch kg, col j)
    float hcur = 0.f;

    short8 afr[4];
    #pragma unroll
    for (int kk = 0; kk < 4; ++kk) afr[kk] = short8{0,0,0,0,0,0,0,0};

    __syncthreads();

    auto step = [&](int t, const unsigned short* src, unsigned short* dst) {
        if (aActive) {
            const char* base = (const char*)src + abase;
            #pragma unroll
            for (int kk = 0; kk < 4; ++kk)
                afr[kk] = *(const short8*)(base + kk * 64);
        }
        f32x4 acc[4] = {};
        #pragma unroll
        for (int kk = 0; kk < 4; ++kk) {
            #pragma unroll
            for (int g = 0; g < 4; ++g)
                acc[g] = __builtin_amdgcn_mfma_f32_16x16x32_bf16(
                             afr[kk], bfrag[g][kk], acc[g], 0, 0, 0);
        }
        const float xv = xT[t][kg];
        const float pg = acc[0][0] + xv * wxv[0] + bv[0];
        const float pi = acc[1][0] + xv * wxv[1] + bv[1];
        const float pf = acc[2][0] + xv * wxv[2] + bv[2];
        const float po = acc[3][0] + xv * wxv[3] + bv[3];
        const float cn = fast_tanh(pg) * fast_sigmoid(pi) + cst * fast_sigmoid(pf);
        cst = cn;
        hcur = fast_tanh(cn) * fast_sigmoid(po);
        *((unsigned short*)dst + kg * 136 + j) = f2bf(hcur);
        __syncthreads();
    };

    for (int t = 0; t < S_LEN; t += 2) {
        step(t,     &hb[0][0][0], &hb[1][0][0]);
        step(t + 1, &hb[1][0][0], &hb[0][0][0]);
    }

    // ---- epilogue: logits = h_last @ W_ph + b_p ----
    hfin[kg][j] = hcur;
    __syncthreads();

    if (tid < 4 * C_DIM) {
        const int b = tid / C_DIM, cc = tid % C_DIM;
        float s = bp[cc];
        #pragma unroll 4
        for (int k = 0; k < H_DIM; ++k) s += hfin[b][k] * Wph[k * C_DIM + cc];
        out[(b0 + b) * C_DIM + cc] = s;
    }
}

extern "C" void kernel_launch(void* const* d_in, const int* in_sizes, int n_in,
                              void* d_out, int out_size, void* d_ws, size_t ws_size,
                              hipStream_t stream) {
    const float* x   = (const float*)d_in[0];
    const float* Wgx = (const float*)d_in[1];
    const float* Wgh = (const float*)d_in[2];
    const float* Wix = (const float*)d_in[3];
    const float* Wih = (const float*)d_in[4];
    const float* Wfx = (const float*)d_in[5];
    const float* Wfh = (const float*)d_in[6];
    const float* Wox = (const float*)d_in[7];
    const float* Woh = (const float*)d_in[8];
    const float* Wph = (const float*)d_in[9];
    const float* bg  = (const float*)d_in[10];
    const float* bi  = (const float*)d_in[11];
    const float* bf  = (const float*)d_in[12];
    const float* bo  = (const float*)d_in[13];
    const float* bp  = (const float*)d_in[14];
    float* out = (float*)d_out;

    lstm_fused<<<dim3(256), dim3(512), 0, stream>>>(
        x, Wgx, Wgh, Wix, Wih, Wfx, Wfh, Wox, Woh, Wph,
        bg, bi, bf, bo, bp, out);
}